// Round 3
// baseline (424.865 us; speedup 1.0000x reference)
//
#include <hip/hip_runtime.h>
#include <math.h>

// NTM read controller, fused single kernel.
// B=1024 blocks (one per batch row), 256 threads (4 waves).
// memory tensor (256 MB) is streamed twice: sim pass + weighted-read pass.

constexpr int Bb = 1024;
constexpr int Ee = 512;
constexpr int Nn = 1024;
constexpr int Mm = 64;
constexpr int Pp = 70;          // M + 6 projection width
constexpr float EPSV = 1e-16f;

__device__ __forceinline__ float softplusf(float x) {
    return (x > 20.f) ? x : log1pf(expf(x));
}

__global__ __launch_bounds__(256) void ntm_fused(
    const float* __restrict__ emb,     // (B,E)
    const float* __restrict__ w_prev,  // (B,N)
    const float* __restrict__ mem,     // (B,N,M)
    const float* __restrict__ Wm,      // (E,P)
    const float* __restrict__ bias,    // (P,)
    float* __restrict__ out_md,        // (B,M)
    float* __restrict__ out_w)         // (B,N)
{
    __shared__ float s_emb[Ee];        // 2 KB
    __shared__ float s_k[Mm];          // key
    __shared__ float s_praw[8];        // proj[64..69]
    __shared__ float s_scal[12];       // knorm,beta,g,s0,s1,s2,y
    __shared__ float s_sim[Nn];        // beta*sim -> later normalized w
    __shared__ float s_wg[Nn];         // gated weights
    __shared__ float s_part[3][Pp];    // proj partials
    __shared__ float s_red[8];         // block reductions
    __shared__ float s_md[4][Mm];      // per-wave memory_data partials

    const int tid  = threadIdx.x;
    const int b    = blockIdx.x;
    const int lane = tid & 63;
    const int wid  = tid >> 6;
    const int sub  = lane >> 4;        // row-within-quad (0..3)
    const int ml   = lane & 15;        // m-group (0..15), 4 floats each

    // ---- Phase 1: embedding row -> LDS (coalesced float4) ----
    const float4* emb4 = reinterpret_cast<const float4*>(emb + (size_t)b * Ee);
    if (tid < Ee / 4) reinterpret_cast<float4*>(s_emb)[tid] = emb4[tid];
    __syncthreads();

    // ---- Phase 2: proj = emb @ W + b (3-way split over E) ----
    if (tid < 3 * Pp) {
        const int j   = tid % Pp;
        const int seg = tid / Pp;
        const int e0 = (seg * Ee) / 3;
        const int e1 = ((seg + 1) * Ee) / 3;
        float acc = 0.f;
        #pragma unroll 4
        for (int e = e0; e < e1; ++e) acc += s_emb[e] * Wm[e * Pp + j];
        s_part[seg][j] = acc;
    }
    __syncthreads();
    if (tid < Pp) {
        float pr = s_part[0][tid] + s_part[1][tid] + s_part[2][tid] + bias[tid];
        if (tid < Mm) s_k[tid] = pr;
        else          s_praw[tid - Mm] = pr;
    }
    __syncthreads();

    // ---- Phase 3: ||k|| (wave 0) + scalar activations (thread 0) ----
    if (wid == 0) {
        float kv = s_k[lane];
        float sq = kv * kv;
        #pragma unroll
        for (int m = 32; m; m >>= 1) sq += __shfl_xor(sq, m, 64);
        if (lane == 0) {
            s_scal[0] = sqrtf(sq);                       // knorm
            const float p0 = s_praw[0], p1 = s_praw[1], p2 = s_praw[2];
            const float p3 = s_praw[3], p4 = s_praw[4], p5 = s_praw[5];
            s_scal[1] = softplusf(p0);                   // beta
            s_scal[2] = 1.f / (1.f + expf(-p1));         // g
            float mx = fmaxf(p2, fmaxf(p3, p4));
            float e2 = expf(p2 - mx), e3 = expf(p3 - mx), e4 = expf(p4 - mx);
            float ss = e2 + e3 + e4;
            s_scal[3] = e2 / ss;                         // s0
            s_scal[4] = e3 / ss;                         // s1
            s_scal[5] = e4 / ss;                         // s2
            s_scal[6] = 1.f + softplusf(p5);             // y
        }
    }
    __syncthreads();

    const float knorm = s_scal[0], beta = s_scal[1], g = s_scal[2];
    const float sh0 = s_scal[3], sh1 = s_scal[4], sh2 = s_scal[5];
    const float yexp = s_scal[6];

    const float* memb = mem + (size_t)b * (Nn * Mm);

    // ---- Phase 4: cosine sims. Wave handles rows [wid*256, +256), 4 rows/iter,
    //      manual 2x unroll (8 rows / 2KB in flight per wave). ----
    {
        const float4 kf = reinterpret_cast<const float4*>(s_k)[ml];
        for (int i = 0; i < 64; i += 2) {
            const int n0 = wid * 256 + i * 4;
            const float4 v0 = reinterpret_cast<const float4*>(memb + n0 * Mm)[lane];
            const float4 v1 = reinterpret_cast<const float4*>(memb + (n0 + 4) * Mm)[lane];
            float d0 = v0.x * kf.x + v0.y * kf.y + v0.z * kf.z + v0.w * kf.w;
            float q0 = v0.x * v0.x + v0.y * v0.y + v0.z * v0.z + v0.w * v0.w;
            float d1 = v1.x * kf.x + v1.y * kf.y + v1.z * kf.z + v1.w * kf.w;
            float q1 = v1.x * v1.x + v1.y * v1.y + v1.z * v1.z + v1.w * v1.w;
            #pragma unroll
            for (int m = 8; m; m >>= 1) {
                d0 += __shfl_xor(d0, m, 16);
                q0 += __shfl_xor(q0, m, 16);
                d1 += __shfl_xor(d1, m, 16);
                q1 += __shfl_xor(q1, m, 16);
            }
            if (ml == 0) {
                s_sim[n0 + sub]     = beta * d0 / (knorm * sqrtf(q0) + EPSV);
                s_sim[n0 + 4 + sub] = beta * d1 / (knorm * sqrtf(q1) + EPSV);
            }
        }
    }
    __syncthreads();

    // ---- Phase 5: softmax over N + gating ----
    float v0 = s_sim[tid], v1 = s_sim[tid + 256], v2 = s_sim[tid + 512], v3 = s_sim[tid + 768];
    float mx = fmaxf(fmaxf(v0, v1), fmaxf(v2, v3));
    #pragma unroll
    for (int m = 32; m; m >>= 1) mx = fmaxf(mx, __shfl_xor(mx, m, 64));
    if (lane == 0) s_red[wid] = mx;
    __syncthreads();
    mx = fmaxf(fmaxf(s_red[0], s_red[1]), fmaxf(s_red[2], s_red[3]));

    float e0 = expf(v0 - mx), e1 = expf(v1 - mx), e2 = expf(v2 - mx), e3 = expf(v3 - mx);
    float lsum = e0 + e1 + e2 + e3;
    #pragma unroll
    for (int m = 32; m; m >>= 1) lsum += __shfl_xor(lsum, m, 64);
    if (lane == 0) s_red[4 + wid] = lsum;
    __syncthreads();
    const float rS = 1.f / (s_red[4] + s_red[5] + s_red[6] + s_red[7]);

    const float* wpb = w_prev + (size_t)b * Nn;
    const float gm1 = 1.f - g;
    s_wg[tid]       = g * (e0 * rS) + gm1 * wpb[tid];
    s_wg[tid + 256] = g * (e1 * rS) + gm1 * wpb[tid + 256];
    s_wg[tid + 512] = g * (e2 * rS) + gm1 * wpb[tid + 512];
    s_wg[tid + 768] = g * (e3 * rS) + gm1 * wpb[tid + 768];
    __syncthreads();

    // ---- Phase 6: shift (circular conv) + sharpen + normalize ----
    float wps[4];
    float psum = 0.f;
    #pragma unroll
    for (int ii = 0; ii < 4; ++ii) {
        const int n = tid + ii * 256;
        const float wt = sh0 * s_wg[(n + 1) & (Nn - 1)]
                       + sh1 * s_wg[n]
                       + sh2 * s_wg[(n - 1) & (Nn - 1)];
        const float wp = powf(wt, yexp);
        wps[ii] = wp;
        psum += wp;
    }
    #pragma unroll
    for (int m = 32; m; m >>= 1) psum += __shfl_xor(psum, m, 64);
    if (lane == 0) s_red[wid] = psum;
    __syncthreads();
    const float rSW = 1.f / (s_red[0] + s_red[1] + s_red[2] + s_red[3] + EPSV);

    float* owb = out_w + (size_t)b * Nn;
    #pragma unroll
    for (int ii = 0; ii < 4; ++ii) {
        const int n = tid + ii * 256;
        const float wv = wps[ii] * rSW;
        owb[n] = wv;
        s_sim[n] = wv;              // reuse s_sim as normalized w for phase 7
    }
    __syncthreads();

    // ---- Phase 7: memory_data = sum_n w[n] * memory[b,n,:] (second stream) ----
    float4 acc = make_float4(0.f, 0.f, 0.f, 0.f);
    #pragma unroll 4
    for (int i = 0; i < 64; ++i) {
        const int n0 = wid * 256 + i * 4;
        const float4 v = reinterpret_cast<const float4*>(memb + n0 * Mm)[lane];
        const float wv = s_sim[n0 + sub];
        acc.x += wv * v.x; acc.y += wv * v.y; acc.z += wv * v.z; acc.w += wv * v.w;
    }
    #pragma unroll
    for (int m = 16; m <= 32; m <<= 1) {
        acc.x += __shfl_xor(acc.x, m, 64);
        acc.y += __shfl_xor(acc.y, m, 64);
        acc.z += __shfl_xor(acc.z, m, 64);
        acc.w += __shfl_xor(acc.w, m, 64);
    }
    if (sub == 0) reinterpret_cast<float4*>(s_md[wid])[ml] = acc;
    __syncthreads();
    if (tid < Mm) {
        out_md[(size_t)b * Mm + tid] =
            s_md[0][tid] + s_md[1][tid] + s_md[2][tid] + s_md[3][tid];
    }
}

extern "C" void kernel_launch(void* const* d_in, const int* in_sizes, int n_in,
                              void* d_out, int out_size, void* d_ws, size_t ws_size,
                              hipStream_t stream) {
    const float* emb    = (const float*)d_in[0];
    const float* w_prev = (const float*)d_in[1];
    const float* mem    = (const float*)d_in[2];
    const float* Wm     = (const float*)d_in[3];
    const float* bias   = (const float*)d_in[4];

    float* out_md = (float*)d_out;                 // (B,M) first
    float* out_w  = out_md + (size_t)Bb * Mm;      // then (B,N)

    ntm_fused<<<dim3(Bb), dim3(256), 0, stream>>>(
        emb, w_prev, mem, Wm, bias, out_md, out_w);
}